// Round 1
// 100.502 us; speedup vs baseline: 1.0408x; 1.0408x over previous
//
#include <hip/hip_runtime.h>
#include <hip/hip_bf16.h>

// cost[i,j] = 0.5*(|x_i|^2 + |y_j|^2) - x_i . y_j
// B=1, N=M=4096, D=128, fp32 in/out.
//
// Strategy: bf16 MFMA for the cross term (4.3 GFLOP -> ~2us at MFMA rate vs
// ~27us on the fp32 vector ALU since CDNA4 has no fp32 MFMA). Norms computed
// in fp32 from the original inputs during LDS staging. Kernel is bound by the
// 64 MB fp32 output write (~11us at 6.3 TB/s).
//
// This revision: OPERAND-SWAPPED MFMA epilogue. mfma(b, a, acc) transposes the
// C/D fragment so each lane's 4 acc regs are 4 CONSECUTIVE output columns of
// one row -> 16 nontemporal global_store_dwordx4 per thread instead of 64
// scalar dword stores (4-row x 64B scattered segments). A/B fragments of
// 16x16x32 share the same per-lane layout, so the swap is layout-legal.

#define NN 4096
#define DD 128
#define TILE 128
#define LDK 136  // bf16 row stride in LDS; 136*2B = 272B = 68 dwords, 68%32=4 -> no 16-way alias

typedef __attribute__((ext_vector_type(8))) short short8;   // 8 bf16 (4 VGPRs)
typedef __attribute__((ext_vector_type(4))) float float4v;  // 4 fp32 acc

static __device__ inline unsigned short f2bf(float v) {
    // round-to-nearest-even fp32 -> bf16 (inputs are finite normals; no NaN path)
    unsigned int u = __float_as_uint(v);
    unsigned int r = (u + 0x7FFFu + ((u >> 16) & 1u)) >> 16;
    return (unsigned short)r;
}

__global__ __launch_bounds__(256, 2)
void cost_kernel(const float* __restrict__ x, const float* __restrict__ y,
                 float* __restrict__ out) {
    __shared__ __align__(16) unsigned short As[TILE * LDK];
    __shared__ __align__(16) unsigned short Bs[TILE * LDK];
    __shared__ float xn[TILE];  // 0.5*|x_row|^2 for the tile's 128 rows
    __shared__ float yn[TILE];  // 0.5*|y_col|^2 for the tile's 128 cols

    const int tid  = threadIdx.x;
    const int brow = blockIdx.y;  // x-tile index (output rows)
    const int bcol = blockIdx.x;  // y-tile index (output cols)

    // ---- stage both tiles: fp32 global -> bf16 LDS, fp32 norms on the side ----
    // Tile is 128 rows x 128 floats = 4096 float4, contiguous in global (D==full row).
    // Each iter: 256 threads read 256 consecutive float4 (perfectly coalesced);
    // 32 consecutive lanes cover exactly one row -> shuffle-reduce |row|^2.
    {
        const float4* sx = reinterpret_cast<const float4*>(x + (size_t)brow * TILE * DD);
        const float4* sy = reinterpret_cast<const float4*>(y + (size_t)bcol * TILE * DD);
        for (int it = 0; it < 16; ++it) {
            int idx = it * 256 + tid;
            int row = idx >> 5;   // 32 float4 per row
            int c4  = idx & 31;
            float4 fx = sx[idx];
            float4 fy = sy[idx];

            ushort4 hx, hy;
            hx.x = f2bf(fx.x); hx.y = f2bf(fx.y); hx.z = f2bf(fx.z); hx.w = f2bf(fx.w);
            hy.x = f2bf(fy.x); hy.y = f2bf(fy.y); hy.z = f2bf(fy.z); hy.w = f2bf(fy.w);
            *reinterpret_cast<ushort4*>(&As[row * LDK + c4 * 4]) = hx;
            *reinterpret_cast<ushort4*>(&Bs[row * LDK + c4 * 4]) = hy;

            float ssx = fx.x * fx.x + fx.y * fx.y + fx.z * fx.z + fx.w * fx.w;
            float ssy = fy.x * fy.x + fy.y * fy.y + fy.z * fy.z + fy.w * fy.w;
            // reduce within each 32-lane row group (xor offsets <32 stay in-half)
            for (int off = 16; off; off >>= 1) {
                ssx += __shfl_xor(ssx, off, 64);
                ssy += __shfl_xor(ssy, off, 64);
            }
            if ((tid & 31) == 0) {
                xn[row] = 0.5f * ssx;
                yn[row] = 0.5f * ssy;
            }
        }
    }
    __syncthreads();

    // ---- MFMA: each of 4 waves computes a 64x64 sub-tile ----
    const int wave = tid >> 6;
    const int lane = tid & 63;
    const int wm = wave >> 1;       // 0..1
    const int wn = wave & 1;        // 0..1
    const int quad = lane >> 4;     // 0..3
    const int l16  = lane & 15;

    float4v acc[4][4] = {};

    for (int kk = 0; kk < 4; ++kk) {
        const int kbase = kk * 32 + quad * 8;
        short8 a[4], b[4];
        for (int mi = 0; mi < 4; ++mi) {
            int r = wm * 64 + mi * 16 + l16;
            a[mi] = *reinterpret_cast<const short8*>(&As[r * LDK + kbase]);
        }
        for (int ni = 0; ni < 4; ++ni) {
            int r = wn * 64 + ni * 16 + l16;
            b[ni] = *reinterpret_cast<const short8*>(&Bs[r * LDK + kbase]);
        }
        // SWAPPED operands: D = B^T-style transpose -> lane&15 indexes the
        // x-row (from a), regs index 4 consecutive y-cols (from b).
        for (int mi = 0; mi < 4; ++mi)
            for (int ni = 0; ni < 4; ++ni)
                acc[mi][ni] = __builtin_amdgcn_mfma_f32_16x16x32_bf16(
                    b[ni], a[mi], acc[mi][ni], 0, 0, 0);
    }

    // ---- epilogue: C = xn + yn - acc, float4 per lane ----
    // Transposed C/D layout (16x16x32): "col" = lane&15 -> x row,
    // "row" = quad*4 + reg -> y col. Lane holds 4 consecutive y-columns.
    for (int mi = 0; mi < 4; ++mi) {
        const int xr = wm * 64 + mi * 16 + l16;       // local x row (per-lane)
        const float xv = xn[xr];
        float* __restrict__ orow =
            out + ((size_t)brow * TILE + xr) * NN + (size_t)bcol * TILE;
        #pragma unroll
        for (int ni = 0; ni < 4; ++ni) {
            const int nc = wn * 64 + ni * 16 + quad * 4;  // local y col base
            const float4v yv = *reinterpret_cast<const float4v*>(&yn[nc]);
            const float4v a4 = acc[mi][ni];
            float4v o;
            o[0] = (xv + yv[0]) - a4[0];
            o[1] = (xv + yv[1]) - a4[1];
            o[2] = (xv + yv[2]) - a4[2];
            o[3] = (xv + yv[3]) - a4[3];
            __builtin_nontemporal_store(o, reinterpret_cast<float4v*>(&orow[nc]));
        }
    }
}

extern "C" void kernel_launch(void* const* d_in, const int* in_sizes, int n_in,
                              void* d_out, int out_size, void* d_ws, size_t ws_size,
                              hipStream_t stream) {
    const float* x = (const float*)d_in[0];
    const float* y = (const float*)d_in[1];
    float* out = (float*)d_out;
    dim3 grid(NN / TILE, NN / TILE);  // (32, 32)
    cost_kernel<<<grid, dim3(256), 0, stream>>>(x, y, out);
}